// Round 9
// baseline (222.949 us; speedup 1.0000x reference)
//
#include <hip/hip_runtime.h>

#define NN 16
#define DD 64
#define SS 32
#define MM 48
// out[(ns*48 + i)*2304 + j*48 + k] ; plane stride 2304 floats = 576 float4

typedef float floatx4 __attribute__((ext_vector_type(4)));

__global__ __launch_bounds__(576, 1) void eq1to3_kernel(
    const float* __restrict__ x,      // (N, D, M)
    const float* __restrict__ coefs,  // (D, S, 4)
    const float* __restrict__ bias,   // [S]
    float* __restrict__ out)          // (N, S, M, M, M)
{
    __shared__ float t_lds[4][MM];

    const int ns = blockIdx.x;        // 0..511  (2 blocks/CU)
    const int n  = ns / SS;
    const int s  = ns % SS;
    const int tid = threadIdx.x;      // 0..575

    // ---- Phase 1: t[b][m] = sum_d coefs[d,s,b]*x[n,d,m]; bias folded into t1 ----
    if (tid < 4 * MM) {
        const int m = tid % MM;
        const int b = tid / MM;
        const float* xp = x + (size_t)n * DD * MM + m;
        const float* cp = coefs + s * 4 + b;
        float acc = 0.f;
        #pragma unroll 8
        for (int d = 0; d < DD; ++d)
            acc += cp[(size_t)d * SS * 4] * xp[(size_t)d * MM];
        if (b == 1) acc += bias[s];
        t_lds[b][m] = acc;
    }
    __syncthreads();

    // ---- Phase 2: register-resident store stream, ZERO loads in the loop ----
    const int j  = tid / (MM / 4);    // 0..47
    const int k4 = tid % (MM / 4);    // 0..11

    floatx4 base;                     // t1[j]+bias + t2[k-quad]
    {
        const float t1j = t_lds[1][j];
        const floatx4 t2q = ((const floatx4*)t_lds[2])[k4];
        base = t2q + t1j;
    }

    // hoist t0[0..47] into registers via 12 static ds_read_b128 (all
    // subsequent indexing compile-time-constant -> stays in VGPRs)
    floatx4 t0q[MM / 4];
    #pragma unroll
    for (int q = 0; q < MM / 4; ++q)
        t0q[q] = ((const floatx4*)t_lds[0])[q];

    floatx4* outp = (floatx4*)(out + (size_t)ns * MM * MM * MM + j * MM + 4 * k4);

    // hot loop: 48 x {4 v_add_f32, 1 global_store_dwordx4} — no loads, no
    // branches, no conditionals; fully unrolled, static t0 indices.
    #pragma unroll
    for (int i = 0; i < MM; ++i) {
        floatx4 v = base + t0q[i / 4][i % 4];
        outp[(size_t)i * (MM * MM / 4)] = v;
    }

    // diag epilogue: 48/576 threads re-store their i==j quad with t3 added.
    // Same thread, same address as the loop store -> program-ordered.
    if ((j >> 2) == k4) {
        floatx4 v = base + t_lds[0][j];
        v[j & 3] += t_lds[3][j];
        outp[(size_t)j * (MM * MM / 4)] = v;
    }
}

extern "C" void kernel_launch(void* const* d_in, const int* in_sizes, int n_in,
                              void* d_out, int out_size, void* d_ws, size_t ws_size,
                              hipStream_t stream) {
    const float* x     = (const float*)d_in[0];
    const float* coefs = (const float*)d_in[1];
    const float* bias  = (const float*)d_in[2];
    float* out = (float*)d_out;

    eq1to3_kernel<<<dim3(NN * SS), dim3(576), 0, stream>>>(x, coefs, bias, out);
}